// Round 1
// baseline (305.973 us; speedup 1.0000x reference)
//
#include <hip/hip_runtime.h>
#include <hip/hip_bf16.h>
#include <stdint.h>

#define DIM 1024

typedef short bf16x8 __attribute__((ext_vector_type(8)));
typedef float f32x4 __attribute__((ext_vector_type(4)));

__device__ __forceinline__ unsigned short f32_to_bf16(float f) {
    union { float f; uint32_t u; } v; v.f = f;
    uint32_t u = v.u;
    u += 0x7FFFu + ((u >> 16) & 1u);   // round-to-nearest-even
    return (unsigned short)(u >> 16);
}

// A = W - W^T; R = I + A (fp32); T0 = bf16(A) (first Taylor term, A-operand
// layout); G = bf16(A^T) = bf16(-A) row-major so B-tiles stage contiguously.
__global__ __launch_bounds__(256) void k_init(const float* __restrict__ W,
        float* __restrict__ R, unsigned short* __restrict__ T0,
        unsigned short* __restrict__ G) {
    int idx = blockIdx.x * 256 + threadIdx.x;
    int i = idx >> 10, j = idx & 1023;
    float a = W[i * DIM + j] - W[j * DIM + i];
    R[idx] = a + ((i == j) ? 1.0f : 0.0f);
    T0[idx] = f32_to_bf16(a);
    G[idx] = f32_to_bf16(-a);
}

// C = (Tin @ A) * scale ; epilogue: R += C (fp32), Tout = bf16(C).
// 64x64 tile, 256 threads = 4 waves in 2x2, each wave 32x32 (2x2 MFMA frags).
__global__ __launch_bounds__(256) void k_taylor(
        const unsigned short* __restrict__ Tin,
        const unsigned short* __restrict__ G,
        float* __restrict__ R, unsigned short* __restrict__ Tout, float scale) {
    __shared__ unsigned short lA[64 * 40];   // +8 pad: 2-way LDS aliasing (free)
    __shared__ unsigned short lB[64 * 40];
    int tid = threadIdx.x;
    int m0 = blockIdx.y * 64, n0 = blockIdx.x * 64;
    int lane = tid & 63, w = tid >> 6;
    int wr = w >> 1, wc = w & 1;
    f32x4 acc[2][2] = {};
    int sr = tid >> 2;           // 0..63
    int sc = (tid & 3) * 8;      // 0,8,16,24
    int ko = (lane >> 4) * 8, rr = lane & 15;
    for (int kb = 0; kb < DIM; kb += 32) {
        *(bf16x8*)&lA[sr * 40 + sc] = *(const bf16x8*)&Tin[(m0 + sr) * DIM + kb + sc];
        *(bf16x8*)&lB[sr * 40 + sc] = *(const bf16x8*)&G[(n0 + sr) * DIM + kb + sc];
        __syncthreads();
        bf16x8 af[2], bfr[2];
        #pragma unroll
        for (int mi = 0; mi < 2; mi++)
            af[mi] = *(const bf16x8*)&lA[(wr * 32 + mi * 16 + rr) * 40 + ko];
        #pragma unroll
        for (int ni = 0; ni < 2; ni++)
            bfr[ni] = *(const bf16x8*)&lB[(wc * 32 + ni * 16 + rr) * 40 + ko];
        #pragma unroll
        for (int mi = 0; mi < 2; mi++)
            #pragma unroll
            for (int ni = 0; ni < 2; ni++)
                acc[mi][ni] = __builtin_amdgcn_mfma_f32_16x16x32_bf16(
                    af[mi], bfr[ni], acc[mi][ni], 0, 0, 0);
        __syncthreads();
    }
    int cc = lane & 15, r0 = (lane >> 4) * 4;
    #pragma unroll
    for (int mi = 0; mi < 2; mi++)
        #pragma unroll
        for (int ni = 0; ni < 2; ni++)
            #pragma unroll
            for (int r = 0; r < 4; r++) {
                int row = m0 + wr * 32 + mi * 16 + r0 + r;
                int col = n0 + wc * 32 + ni * 16 + cc;
                float v = acc[mi][ni][r] * scale;
                R[row * DIM + col] += v;          // exclusive per lane, safe
                Tout[row * DIM + col] = f32_to_bf16(v);
            }
}

// Rt[j][i] = bf16(R[i][j]) — LDS-tiled transpose+convert.
__global__ __launch_bounds__(256) void k_transpose(const float* __restrict__ R,
        unsigned short* __restrict__ Rt) {
    __shared__ float t[32][33];
    int bx = blockIdx.x * 32, by = blockIdx.y * 32;
    int tx = threadIdx.x & 31, ty = threadIdx.x >> 5;
    #pragma unroll
    for (int r = ty; r < 32; r += 8)
        t[r][tx] = R[(by + r) * DIM + bx + tx];
    __syncthreads();
    #pragma unroll
    for (int r = ty; r < 32; r += 8)
        Rt[(bx + r) * DIM + by + tx] = f32_to_bf16(t[tx][r]);
}

// Out(16384x1024) = X @ R.  X fp32 converted to bf16 during LDS staging.
// 128x128 tile, 4 waves 2x2, each wave 64x64 = 4x4 frags of 16x16x32.
__global__ __launch_bounds__(256) void k_biggemm(const float* __restrict__ X,
        const unsigned short* __restrict__ Rt, float* __restrict__ Out) {
    __shared__ unsigned short lX[128 * 40];
    __shared__ unsigned short lB[128 * 40];
    int tid = threadIdx.x;
    int m0 = blockIdx.y * 128, n0 = blockIdx.x * 128;
    int lane = tid & 63, w = tid >> 6;
    int wr = w >> 1, wc = w & 1;
    f32x4 acc[4][4] = {};
    int sr = tid >> 1;           // 0..127
    int sc = (tid & 1) * 16;     // 0 or 16
    int ko = (lane >> 4) * 8, rr = lane & 15;
    for (int kb = 0; kb < DIM; kb += 32) {
        const float* xp = &X[(m0 + sr) * DIM + kb + sc];
        float xv[16];
        *(f32x4*)&xv[0]  = *(const f32x4*)&xp[0];
        *(f32x4*)&xv[4]  = *(const f32x4*)&xp[4];
        *(f32x4*)&xv[8]  = *(const f32x4*)&xp[8];
        *(f32x4*)&xv[12] = *(const f32x4*)&xp[12];
        unsigned short xb[16];
        #pragma unroll
        for (int q = 0; q < 16; q++) xb[q] = f32_to_bf16(xv[q]);
        *(bf16x8*)&lX[sr * 40 + sc]     = *(bf16x8*)&xb[0];
        *(bf16x8*)&lX[sr * 40 + sc + 8] = *(bf16x8*)&xb[8];
        *(bf16x8*)&lB[sr * 40 + sc]     = *(const bf16x8*)&Rt[(n0 + sr) * DIM + kb + sc];
        *(bf16x8*)&lB[sr * 40 + sc + 8] = *(const bf16x8*)&Rt[(n0 + sr) * DIM + kb + sc + 8];
        __syncthreads();
        bf16x8 af[4], bfr[4];
        #pragma unroll
        for (int mi = 0; mi < 4; mi++)
            af[mi] = *(const bf16x8*)&lX[(wr * 64 + mi * 16 + rr) * 40 + ko];
        #pragma unroll
        for (int ni = 0; ni < 4; ni++)
            bfr[ni] = *(const bf16x8*)&lB[(wc * 64 + ni * 16 + rr) * 40 + ko];
        #pragma unroll
        for (int mi = 0; mi < 4; mi++)
            #pragma unroll
            for (int ni = 0; ni < 4; ni++)
                acc[mi][ni] = __builtin_amdgcn_mfma_f32_16x16x32_bf16(
                    af[mi], bfr[ni], acc[mi][ni], 0, 0, 0);
        __syncthreads();
    }
    int cc = lane & 15, r0 = (lane >> 4) * 4;
    #pragma unroll
    for (int mi = 0; mi < 4; mi++)
        #pragma unroll
        for (int ni = 0; ni < 4; ni++)
            #pragma unroll
            for (int r = 0; r < 4; r++) {
                int row = m0 + wr * 64 + mi * 16 + r0 + r;
                int col = n0 + wc * 64 + ni * 16 + cc;
                Out[row * DIM + col] = acc[mi][ni][r];
            }
}

extern "C" void kernel_launch(void* const* d_in, const int* in_sizes, int n_in,
                              void* d_out, int out_size, void* d_ws, size_t ws_size,
                              hipStream_t stream) {
    const float* X = (const float*)d_in[0];        // 4*4096*1024 fp32
    const float* W = (const float*)d_in[1];        // 1024*1024 fp32
    float* Out = (float*)d_out;                    // 16384*1024 fp32
    char* ws = (char*)d_ws;
    float* R            = (float*)ws;                          // 4 MB fp32
    unsigned short* G   = (unsigned short*)(ws + (4u << 20));  // 2 MB bf16 (A^T)
    unsigned short* T0b = (unsigned short*)(ws + (6u << 20));  // 2 MB
    unsigned short* T1b = (unsigned short*)(ws + (8u << 20));  // 2 MB
    unsigned short* Rt  = (unsigned short*)(ws + (10u << 20)); // 2 MB bf16 (R^T)

    k_init<<<dim3(DIM * DIM / 256), 256, 0, stream>>>(W, R, T0b, G);

    unsigned short* tin = T0b;
    unsigned short* tout = T1b;
    for (int k = 2; k <= 8; k++) {   // degree-8 Taylor: trunc err ~1e-6
        k_taylor<<<dim3(16, 16), 256, 0, stream>>>(tin, G, R, tout, 1.0f / (float)k);
        unsigned short* tmp = tin; tin = tout; tout = tmp;
    }

    k_transpose<<<dim3(32, 32), 256, 0, stream>>>(R, Rt);
    k_biggemm<<<dim3(8, 128), 256, 0, stream>>>(X, Rt, Out);
}

// Round 2
// 199.074 us; speedup vs baseline: 1.5370x; 1.5370x over previous
//
#include <hip/hip_runtime.h>
#include <stdint.h>

#define DIM 1024
#define GLOBAL_AS __attribute__((address_space(1)))
#define LDS_AS __attribute__((address_space(3)))

typedef short bf16x8 __attribute__((ext_vector_type(8)));
typedef float f32x4 __attribute__((ext_vector_type(4)));

// Taylor 1/k! coefficients
#define C3 0.16666667f
#define C4 0.041666668f
#define C5 0.008333334f
#define C6 0.0013888889f
#define C7 1.9841270e-4f
#define C8 2.4801587e-5f

__device__ __forceinline__ unsigned short f32_to_bf16(float f) {
    union { float f; uint32_t u; } v; v.f = f;
    uint32_t u = v.u;
    u += 0x7FFFu + ((u >> 16) & 1u);   // round-to-nearest-even
    return (unsigned short)(u >> 16);
}
__device__ __forceinline__ float bf16_to_f32(unsigned short u) {
    union { uint32_t u; float f; } v; v.u = ((uint32_t)u) << 16;
    return v.f;
}

// async global->LDS, 16B per lane. LDS dst MUST be wave-uniform base + lane*16.
__device__ __forceinline__ void async16(const void* g, void* l) {
    __builtin_amdgcn_global_load_lds((GLOBAL_AS const void*)g,
                                     (LDS_AS void*)l, 16, 0, 0);
}

// A = W - W^T; Ab = bf16(A) (A-operand), G = bf16(A^T) = bf16(-A) (B-operand).
__global__ __launch_bounds__(256) void k_init(const float* __restrict__ W,
        unsigned short* __restrict__ Ab, unsigned short* __restrict__ G) {
    int idx = blockIdx.x * 256 + threadIdx.x;
    int i = idx >> 10, j = idx & 1023;
    float a = W[i * DIM + j] - W[j * DIM + i];
    Ab[idx] = f32_to_bf16(a);
    G[idx]  = f32_to_bf16(-a);
}

// Xb = bf16(X), 8 elems/thread.
__global__ __launch_bounds__(256) void k_convert(const float* __restrict__ X,
        unsigned short* __restrict__ Xb) {
    int id = blockIdx.x * 256 + threadIdx.x;
    const f32x4* p = (const f32x4*)(X + (size_t)id * 8);
    f32x4 v0 = p[0], v1 = p[1];
    unsigned short o[8];
    #pragma unroll
    for (int q = 0; q < 4; q++) { o[q] = f32_to_bf16(v0[q]); o[4 + q] = f32_to_bf16(v1[q]); }
    *(bf16x8*)&Xb[(size_t)id * 8] = *(bf16x8*)o;
}

// 1024^3 GEMM: acc = P(row-major bf16) * Q, with Q supplied as Q^T row-major (Qt).
// 64x64 tile, 256 blocks, BK=256 (4 k-steps), global_load_lds staging,
// XOR-swizzled LDS chunks (chunk c stored at c ^ (row&7)) -> conflict-free b128 reads.
// MODE 1: out1=bf16(acc)=A2b, out2=bf16(C6*I - C7*A + C8*acc)=B1t (q2^T, exact by symmetry)
// MODE 2: out1=bf16(acc)=A3b
// MODE 3: v=acc + C3*I + C4*A + C5*A2; LDS-transpose; out1=bf16(v^T)=B2t
// MODE 4: v=acc + I + A + 0.5*A2;      LDS-transpose; out1=bf16(v^T)=Rt
template<int MODE>
__global__ __launch_bounds__(256) void k_pgemm(
        const unsigned short* __restrict__ P,
        const unsigned short* __restrict__ Qt,
        const unsigned short* __restrict__ Ab,
        const unsigned short* __restrict__ A2b,
        unsigned short* __restrict__ out1,
        unsigned short* __restrict__ out2) {
    __shared__ unsigned short lP[64 * 256];   // 32 KB
    __shared__ unsigned short lQ[64 * 256];   // 32 KB
    int tid = threadIdx.x;
    int m0 = blockIdx.y * 64, n0 = blockIdx.x * 64;
    int lane = tid & 63, w = tid >> 6;
    int wr = w >> 1, wc = w & 1;
    int rr = lane & 15, ko = lane >> 4;
    f32x4 acc[2][2] = {};
    for (int ks = 0; ks < 4; ks++) {
        int kb = ks * 256;
        #pragma unroll
        for (int i = 0; i < 8; i++) {
            int l = i * 256 + tid;
            int r = l >> 5, cst = l & 31;
            int cd = cst ^ (r & 7);            // data chunk loaded into slot cst
            async16(&P[(m0 + r) * DIM + kb + cd * 8], &lP[l * 8]);
            async16(&Qt[(n0 + r) * DIM + kb + cd * 8], &lQ[l * 8]);
        }
        __syncthreads();
        #pragma unroll
        for (int s = 0; s < 8; s++) {
            int cd = s * 4 + ko;
            bf16x8 af[2], bq[2];
            #pragma unroll
            for (int mi = 0; mi < 2; mi++) {
                int ra = wr * 32 + mi * 16 + rr;
                af[mi] = *(const bf16x8*)&lP[ra * 256 + ((cd ^ (ra & 7)) * 8)];
            }
            #pragma unroll
            for (int ni = 0; ni < 2; ni++) {
                int rb = wc * 32 + ni * 16 + rr;
                bq[ni] = *(const bf16x8*)&lQ[rb * 256 + ((cd ^ (rb & 7)) * 8)];
            }
            #pragma unroll
            for (int mi = 0; mi < 2; mi++)
                #pragma unroll
                for (int ni = 0; ni < 2; ni++)
                    acc[mi][ni] = __builtin_amdgcn_mfma_f32_16x16x32_bf16(
                        af[mi], bq[ni], acc[mi][ni], 0, 0, 0);
        }
        __syncthreads();
    }
    if (MODE == 1 || MODE == 2) {
        #pragma unroll
        for (int mi = 0; mi < 2; mi++)
            #pragma unroll
            for (int ni = 0; ni < 2; ni++)
                #pragma unroll
                for (int q = 0; q < 4; q++) {
                    int rl = wr * 32 + mi * 16 + ko * 4 + q;
                    int cl = wc * 32 + ni * 16 + rr;
                    int gi = (m0 + rl) * DIM + n0 + cl;
                    float v = acc[mi][ni][q];
                    out1[gi] = f32_to_bf16(v);
                    if (MODE == 1) {
                        float a = bf16_to_f32(Ab[gi]);
                        float d = (m0 + rl == n0 + cl) ? C6 : 0.0f;
                        out2[gi] = f32_to_bf16(d - C7 * a + C8 * v);
                    }
                }
    } else {
        float* tb = (float*)lP;   // 64*65*4 = 16.6 KB, LDS free after last barrier
        #pragma unroll
        for (int mi = 0; mi < 2; mi++)
            #pragma unroll
            for (int ni = 0; ni < 2; ni++)
                #pragma unroll
                for (int q = 0; q < 4; q++) {
                    int rl = wr * 32 + mi * 16 + ko * 4 + q;
                    int cl = wc * 32 + ni * 16 + rr;
                    int gi = (m0 + rl) * DIM + n0 + cl;
                    float a = bf16_to_f32(Ab[gi]);
                    float a2 = bf16_to_f32(A2b[gi]);
                    float d = (m0 + rl == n0 + cl) ? 1.0f : 0.0f;
                    float v;
                    if (MODE == 3) v = acc[mi][ni][q] + C3 * d + C4 * a + C5 * a2;
                    else           v = acc[mi][ni][q] + d + a + 0.5f * a2;
                    tb[cl * 65 + rl] = v;
                }
        __syncthreads();
        #pragma unroll
        for (int q = 0; q < 16; q++) {
            int l = tid * 16 + q;
            int orow = l >> 6, ocol = l & 63;
            out1[(n0 + orow) * DIM + m0 + ocol] = f32_to_bf16(tb[orow * 65 + ocol]);
        }
    }
}

// Out(16384x1024) = Xb(bf16) @ R, R supplied as R^T row-major bf16 (Rtb).
// 128(m) x 256(n) tiles, grid 512 1-D: mt = id&127, nt = id>>7 so that the 4
// n-columns of one m-tile land on the SAME XCD (id%8 == mt%8) -> X tile fetched
// once per XCD L2. BK=32, global_load_lds, XOR swizzle ((r>>1)&3).
__global__ __launch_bounds__(256) void k_biggemm(
        const unsigned short* __restrict__ Xb,
        const unsigned short* __restrict__ Rtb,
        float* __restrict__ Out) {
    __shared__ unsigned short lX[128 * 32];   // 8 KB
    __shared__ unsigned short lB[256 * 32];   // 16 KB
    int tid = threadIdx.x;
    int bid = blockIdx.x;
    int m0 = (bid & 127) * 128, n0 = (bid >> 7) * 256;
    int lane = tid & 63, w = tid >> 6;
    int wr = w >> 1, wc = w & 1;
    int rr = lane & 15, ko = lane >> 4;
    f32x4 acc[4][8] = {};
    for (int kb = 0; kb < DIM; kb += 32) {
        #pragma unroll
        for (int i = 0; i < 2; i++) {
            int l = i * 256 + tid;
            int r = l >> 2, cst = l & 3;
            int cd = cst ^ ((r >> 1) & 3);
            async16(&Xb[(m0 + r) * DIM + kb + cd * 8], &lX[l * 8]);
        }
        #pragma unroll
        for (int i = 0; i < 4; i++) {
            int l = i * 256 + tid;
            int r = l >> 2, cst = l & 3;
            int cd = cst ^ ((r >> 1) & 3);
            async16(&Rtb[(n0 + r) * DIM + kb + cd * 8], &lB[l * 8]);
        }
        __syncthreads();
        bf16x8 af[4], bq[8];
        #pragma unroll
        for (int mi = 0; mi < 4; mi++) {
            int ra = wr * 64 + mi * 16 + rr;
            af[mi] = *(const bf16x8*)&lX[ra * 32 + ((ko ^ ((ra >> 1) & 3)) * 8)];
        }
        #pragma unroll
        for (int ni = 0; ni < 8; ni++) {
            int rb = wc * 128 + ni * 16 + rr;
            bq[ni] = *(const bf16x8*)&lB[rb * 32 + ((ko ^ ((rb >> 1) & 3)) * 8)];
        }
        #pragma unroll
        for (int mi = 0; mi < 4; mi++)
            #pragma unroll
            for (int ni = 0; ni < 8; ni++)
                acc[mi][ni] = __builtin_amdgcn_mfma_f32_16x16x32_bf16(
                    af[mi], bq[ni], acc[mi][ni], 0, 0, 0);
        __syncthreads();
    }
    #pragma unroll
    for (int mi = 0; mi < 4; mi++)
        #pragma unroll
        for (int ni = 0; ni < 8; ni++)
            #pragma unroll
            for (int q = 0; q < 4; q++) {
                int row = m0 + wr * 64 + mi * 16 + ko * 4 + q;
                int col = n0 + wc * 128 + ni * 16 + rr;
                Out[(size_t)row * DIM + col] = acc[mi][ni][q];
            }
}

// Fallback when ws too small for Xb: identical but X staged fp32->bf16 via VALU.
__global__ __launch_bounds__(256) void k_biggemm_cvt(
        const float* __restrict__ X,
        const unsigned short* __restrict__ Rtb,
        float* __restrict__ Out) {
    __shared__ unsigned short lX[128 * 32];
    __shared__ unsigned short lB[256 * 32];
    int tid = threadIdx.x;
    int bid = blockIdx.x;
    int m0 = (bid & 127) * 128, n0 = (bid >> 7) * 256;
    int lane = tid & 63, w = tid >> 6;
    int wr = w >> 1, wc = w & 1;
    int rr = lane & 15, ko = lane >> 4;
    f32x4 acc[4][8] = {};
    int xr = tid >> 1, xh = tid & 1;
    int q3 = (xr >> 1) & 3;
    for (int kb = 0; kb < DIM; kb += 32) {
        {
            const float* xp = &X[(size_t)(m0 + xr) * DIM + kb + xh * 16];
            float xv[16];
            *(f32x4*)&xv[0] = *(const f32x4*)&xp[0];
            *(f32x4*)&xv[4] = *(const f32x4*)&xp[4];
            *(f32x4*)&xv[8] = *(const f32x4*)&xp[8];
            *(f32x4*)&xv[12] = *(const f32x4*)&xp[12];
            unsigned short xs[16];
            #pragma unroll
            for (int q = 0; q < 16; q++) xs[q] = f32_to_bf16(xv[q]);
            *(bf16x8*)&lX[xr * 32 + (((2 * xh) ^ q3) * 8)]     = *(bf16x8*)&xs[0];
            *(bf16x8*)&lX[xr * 32 + (((2 * xh + 1) ^ q3) * 8)] = *(bf16x8*)&xs[8];
        }
        #pragma unroll
        for (int i = 0; i < 4; i++) {
            int l = i * 256 + tid;
            int r = l >> 2, cst = l & 3;
            int cd = cst ^ ((r >> 1) & 3);
            async16(&Rtb[(n0 + r) * DIM + kb + cd * 8], &lB[l * 8]);
        }
        __syncthreads();
        bf16x8 af[4], bq[8];
        #pragma unroll
        for (int mi = 0; mi < 4; mi++) {
            int ra = wr * 64 + mi * 16 + rr;
            af[mi] = *(const bf16x8*)&lX[ra * 32 + ((ko ^ ((ra >> 1) & 3)) * 8)];
        }
        #pragma unroll
        for (int ni = 0; ni < 8; ni++) {
            int rb = wc * 128 + ni * 16 + rr;
            bq[ni] = *(const bf16x8*)&lB[rb * 32 + ((ko ^ ((rb >> 1) & 3)) * 8)];
        }
        #pragma unroll
        for (int mi = 0; mi < 4; mi++)
            #pragma unroll
            for (int ni = 0; ni < 8; ni++)
                acc[mi][ni] = __builtin_amdgcn_mfma_f32_16x16x32_bf16(
                    af[mi], bq[ni], acc[mi][ni], 0, 0, 0);
        __syncthreads();
    }
    #pragma unroll
    for (int mi = 0; mi < 4; mi++)
        #pragma unroll
        for (int ni = 0; ni < 8; ni++)
            #pragma unroll
            for (int q = 0; q < 4; q++) {
                int row = m0 + wr * 64 + mi * 16 + ko * 4 + q;
                int col = n0 + wc * 128 + ni * 16 + rr;
                Out[(size_t)row * DIM + col] = acc[mi][ni][q];
            }
}

extern "C" void kernel_launch(void* const* d_in, const int* in_sizes, int n_in,
                              void* d_out, int out_size, void* d_ws, size_t ws_size,
                              hipStream_t stream) {
    const float* X = (const float*)d_in[0];        // 4*4096*1024 fp32
    const float* W = (const float*)d_in[1];        // 1024*1024 fp32
    float* Out = (float*)d_out;                    // 16384*1024 fp32
    char* ws = (char*)d_ws;
    const size_t MB = 1u << 20;
    unsigned short* Ab   = (unsigned short*)(ws + 0 * MB);
    unsigned short* G    = (unsigned short*)(ws + 2 * MB);
    unsigned short* A2b  = (unsigned short*)(ws + 4 * MB);
    unsigned short* A3b  = (unsigned short*)(ws + 6 * MB);
    unsigned short* B1tb = (unsigned short*)(ws + 8 * MB);
    unsigned short* B2tb = (unsigned short*)(ws + 10 * MB);
    unsigned short* Rtb  = (unsigned short*)(ws + 12 * MB);
    unsigned short* Xb   = (unsigned short*)(ws + 14 * MB);  // 32 MB

    k_init<<<4096, 256, 0, stream>>>(W, Ab, G);
    // Paterson-Stockmeyer: p(A)=q0 + A3*(q1 + A3*q2), qi deg-2 in {I,A,A2}
    k_pgemm<1><<<dim3(16, 16), 256, 0, stream>>>(Ab, G, Ab, nullptr, A2b, B1tb);     // A2, q2^T
    k_pgemm<2><<<dim3(16, 16), 256, 0, stream>>>(Ab, A2b, nullptr, nullptr, A3b, nullptr); // A3 (A2^T=A2)
    k_pgemm<3><<<dim3(16, 16), 256, 0, stream>>>(A3b, B1tb, Ab, A2b, B2tb, nullptr); // B2^T
    k_pgemm<4><<<dim3(16, 16), 256, 0, stream>>>(A3b, B2tb, Ab, A2b, Rtb, nullptr);  // R^T

    if (ws_size >= 46 * MB) {
        k_convert<<<8192, 256, 0, stream>>>(X, Xb);
        k_biggemm<<<512, 256, 0, stream>>>(Xb, Rtb, Out);
    } else {
        k_biggemm_cvt<<<512, 256, 0, stream>>>(X, Rtb, Out);
    }
}